// Round 1
// baseline (450.241 us; speedup 1.0000x reference)
//
#include <hip/hip_runtime.h>
#include <stdint.h>

#define N_DET 20000
#define N_CLS 80
#define TOPK  1000
#define CONF  0.05f
#define NMST  0.5f
#define CAND  2048

typedef unsigned long long u64;
typedef unsigned int u32;

__device__ inline u64 shfl64(u64 v, int src) {
  int lo = __shfl((int)(u32)v, src, 64);
  int hi = __shfl((int)(v >> 32), src, 64);
  return ((u64)(u32)hi << 32) | (u32)lo;
}

// ---------------------------------------------------------------------------
// K1: per-class exact top-1000 (score desc, index asc tie-break).
// 3-level 256-bin radix select on float bits, then bitonic sort of candidates.
// ---------------------------------------------------------------------------
__global__ __launch_bounds__(256) void k_topk(
    const float* __restrict__ scores, const float* __restrict__ boxes,
    float* __restrict__ top_s, float* __restrict__ boxes_s) {
  const int c = blockIdx.x, t = threadIdx.x;
  __shared__ u32 hist[256];
  __shared__ u32 sfx[256];
  __shared__ int sB;
  __shared__ u32 scnt;
  __shared__ u64 keys[CAND];

  u32 T = 0;
  u32 target = TOPK;
  for (int level = 0; level < 3; ++level) {
    const int shift = 24 - 8 * level;
    hist[t] = 0;
    __syncthreads();
    for (int i = t; i < N_DET; i += 256) {
      u32 b = __float_as_uint(scores[i * N_CLS + c]);
      bool match = (level == 0) || ((b >> (shift + 8)) == (T >> (shift + 8)));
      if (match) atomicAdd(&hist[(b >> shift) & 0xFF], 1u);
    }
    __syncthreads();
    sfx[t] = hist[t];
    __syncthreads();
    for (int off = 1; off < 256; off <<= 1) {
      u32 v = (t + off < 256) ? sfx[t + off] : 0u;
      __syncthreads();
      sfx[t] += v;
      __syncthreads();
    }
    // largest bin B with suffix count >= target (suffix is non-increasing)
    if (sfx[t] >= target && (t == 255 || sfx[t + 1] < target)) sB = t;
    __syncthreads();
    int B = sB;
    u32 above = (B == 255) ? 0u : sfx[B + 1];
    T |= ((u32)B) << shift;
    target -= above;
    __syncthreads();
  }
  if (t == 0) scnt = 0;
  __syncthreads();
  for (int i = t; i < N_DET; i += 256) {
    u32 b = __float_as_uint(scores[i * N_CLS + c]);
    if (b >= T) {
      u32 p = atomicAdd(&scnt, 1u);
      if (p < CAND) keys[p] = ((u64)b << 32) | (u32)(~(u32)i);
    }
  }
  __syncthreads();
  u32 cnt = scnt < CAND ? scnt : CAND;
  for (int i = t; i < CAND; i += 256)
    if (i >= (int)cnt) keys[i] = 0ull;
  __syncthreads();
  // bitonic sort, descending
  for (int k = 2; k <= CAND; k <<= 1)
    for (int j = k >> 1; j > 0; j >>= 1) {
      for (int p = t; p < CAND / 2; p += 256) {
        int i  = ((p & ~(j - 1)) << 1) | (p & (j - 1));
        int ix = i | j;
        bool up = (i & k) == 0;
        u64 a = keys[i], b = keys[ix];
        if (up ? (a < b) : (a > b)) { keys[i] = b; keys[ix] = a; }
      }
      __syncthreads();
    }
  for (int i = t; i < TOPK; i += 256) {
    u64 kk = keys[i];
    u32 bits = (u32)(kk >> 32);
    u32 idx = ~(u32)kk;
    if (kk == 0ull) idx = 0;  // pad entry (pathological only)
    top_s[c * TOPK + i] = __uint_as_float(bits);
    float4 bx = ((const float4*)boxes)[idx];
    ((float4*)boxes_s)[c * TOPK + i] = bx;
  }
}

// ---------------------------------------------------------------------------
// K2: suppression bitmask. mask[i] bit j set iff j>i and iou(i,j)>0.5.
// 16 u64 words per row. Grid: (classes_in_chunk, 25 row-blocks of 40 rows).
// ---------------------------------------------------------------------------
__global__ __launch_bounds__(256) void k_mask(
    const float* __restrict__ boxes_s, u64* __restrict__ mask, int c0) {
  const int c = c0 + blockIdx.x;
  const int tid = threadIdx.x;
  const int wave = tid >> 6, lane = tid & 63;
  __shared__ float4 sbox[TOPK];
  __shared__ float sarea[TOPK];
  for (int i = tid; i < TOPK; i += 256) {
    float4 b = ((const float4*)boxes_s)[c * TOPK + i];
    sbox[i] = b;
    sarea[i] = (b.z - b.x) * (b.w - b.y);
  }
  __syncthreads();
  for (int rr = 0; rr < 10; ++rr) {
    const int i = blockIdx.y * 40 + wave * 10 + rr;
    const float4 bi = sbox[i];
    const float ai = sarea[i];
    u64 myword = 0;
    for (int s = 0; s < 16; ++s) {
      int j = s * 64 + lane;
      bool sup = false;
      if (j < TOPK && j > i) {
        #pragma clang fp contract(off)
        float4 bj = sbox[j];
        float iw = fmaxf(fminf(bi.z, bj.z) - fmaxf(bi.x, bj.x), 0.0f);
        float ih = fmaxf(fminf(bi.w, bj.w) - fmaxf(bi.y, bj.y), 0.0f);
        float inter = iw * ih;
        float iou = inter / (ai + sarea[j] - inter + 1e-9f);
        sup = iou > NMST;
      }
      u64 bal = __ballot(sup);
      if (lane == s) myword = bal;
    }
    if (lane < 16)
      mask[((size_t)blockIdx.x * TOPK + i) * 16 + lane] = myword;
  }
}

// ---------------------------------------------------------------------------
// K3: serial greedy sweep, one wave per class. Keep bits in lanes 0..15,
// mask rows prefetched 8 deep. Then compact first <=100 kept scores.
// ---------------------------------------------------------------------------
__global__ __launch_bounds__(64) void k_sweep(
    const float* __restrict__ top_s, const u64* __restrict__ mask,
    float* __restrict__ cls_out, int c0) {
  const int c = c0 + blockIdx.x;
  const int lane = threadIdx.x;
  const u64* M = mask + (size_t)blockIdx.x * TOPK * 16;
  u64 keepw = 0;
  for (int s = 0; s < 16; ++s) {
    int j = s * 64 + lane;
    bool valid = (j < TOPK) && (top_s[c * TOPK + j] > CONF);
    u64 bal = __ballot(valid);
    if (lane == s) keepw = bal;
  }
  const bool ld = lane < 16;
  u64 rbuf[8];
  #pragma unroll
  for (int d = 0; d < 8; ++d)
    rbuf[d] = ld ? M[(size_t)d * 16 + lane] : 0ull;
  for (int ib = 0; ib < TOPK; ib += 8) {
    #pragma unroll
    for (int d = 0; d < 8; ++d) {
      const int i = ib + d;
      u64 w = shfl64(keepw, i >> 6);
      if ((w >> (i & 63)) & 1ull) keepw &= ~rbuf[d];
      int nx = ib + 8 + d;
      rbuf[d] = (ld && nx < TOPK) ? M[(size_t)nx * 16 + lane] : 0ull;
    }
  }
  // compact first <=100 kept scores (sorted order preserved)
  int base = 0;
  for (int s = 0; s < 16; ++s) {
    u64 w = shfl64(keepw, s);
    int pos = base + __popcll(w & ((1ull << lane) - 1ull));
    if (((w >> lane) & 1ull) && pos < 100)
      cls_out[c * 128 + pos] = top_s[c * TOPK + s * 64 + lane];
    base += __popcll(w);
  }
}

// ---------------------------------------------------------------------------
// K4: global top-100 of 80 x (top-100 per class), bitonic sort 8192 in LDS.
// ---------------------------------------------------------------------------
__global__ __launch_bounds__(512) void k_final(
    const float* __restrict__ cls_out, float* __restrict__ out) {
  __shared__ float v[8192];
  const int t = threadIdx.x;
  for (int i = t; i < 8192; i += 512) {
    float x = 0.0f;
    if (i < 8000) x = cls_out[(i / 100) * 128 + (i % 100)];
    v[i] = x;
  }
  __syncthreads();
  for (int k = 2; k <= 8192; k <<= 1)
    for (int j = k >> 1; j > 0; j >>= 1) {
      for (int p = t; p < 4096; p += 512) {
        int i  = ((p & ~(j - 1)) << 1) | (p & (j - 1));
        int ix = i | j;
        bool up = (i & k) == 0;
        float a = v[i], b = v[ix];
        if (up ? (a < b) : (a > b)) { v[i] = b; v[ix] = a; }
      }
      __syncthreads();
    }
  if (t < 100) out[t] = v[t];
}

// ---------------------------------------------------------------------------
// Workspace layout:
//   top_s   : 80*1000 f32            @ 0        (320000 B)
//   boxes_s : 80*1000 float4         @ 320000   (1280000 B)
//   cls_out : 80*128 f32             @ 1600000  (40960 B)
//   mask    : CH*1000*16 u64         @ 1640960  (128000 B per class)
// ---------------------------------------------------------------------------
extern "C" void kernel_launch(void* const* d_in, const int* in_sizes, int n_in,
                              void* d_out, int out_size, void* d_ws, size_t ws_size,
                              hipStream_t stream) {
  const float* scores = (const float*)d_in[0];
  const float* boxes  = (const float*)d_in[1];
  float* out = (float*)d_out;
  char* ws = (char*)d_ws;
  float* top_s   = (float*)(ws);
  float* boxes_s = (float*)(ws + 320000);
  float* cls_out = (float*)(ws + 1600000);
  u64*   mask    = (u64*)(ws + 1640960);
  size_t maskBytes = ws_size > 1640960 ? ws_size - 1640960 : 0;
  int CH = (int)(maskBytes / (TOPK * 16 * sizeof(u64)));
  if (CH < 1) CH = 1;
  if (CH > N_CLS) CH = N_CLS;

  hipMemsetAsync(cls_out, 0, N_CLS * 128 * sizeof(float), stream);
  k_topk<<<N_CLS, 256, 0, stream>>>(scores, boxes, top_s, boxes_s);
  for (int c0 = 0; c0 < N_CLS; c0 += CH) {
    int n = (N_CLS - c0) < CH ? (N_CLS - c0) : CH;
    k_mask<<<dim3(n, 25), 256, 0, stream>>>(boxes_s, mask, c0);
    k_sweep<<<n, 64, 0, stream>>>(top_s, mask, cls_out, c0);
  }
  k_final<<<1, 512, 0, stream>>>(cls_out, out);
}

// Round 2
// 440.971 us; speedup vs baseline: 1.0210x; 1.0210x over previous
//
#include <hip/hip_runtime.h>
#include <stdint.h>

#define N_DET 20000
#define N_CLS 80
#define TOPK  1000
#define CONF  0.05f
#define NMST  0.5f
#define CAND  2048

typedef unsigned long long u64;
typedef unsigned int u32;

__device__ inline u64 shfl64(u64 v, int src) {
  int lo = __shfl((int)(u32)v, src, 64);
  int hi = __shfl((int)(v >> 32), src, 64);
  return ((u64)(u32)hi << 32) | (u32)lo;
}

// ---------------------------------------------------------------------------
// Transpose scores [N_DET][N_CLS] -> scores_t [N_CLS][N_DET].
// Coalesced reads (flat), coalesced writes (128-float runs per class).
// LDS tile padded to stride 81 to avoid bank conflicts on the strided read.
// ---------------------------------------------------------------------------
__global__ __launch_bounds__(256) void k_transpose(
    const float* __restrict__ scores, float* __restrict__ scores_t) {
  __shared__ float tile[128 * 81];
  const int d0 = blockIdx.x * 128;
  int lim = N_DET - d0; if (lim > 128) lim = 128;
  const int n = lim * N_CLS;
  for (int i = threadIdx.x; i < n; i += 256) {
    int d = i / N_CLS, c = i % N_CLS;
    tile[d * 81 + c] = scores[(size_t)d0 * N_CLS + i];
  }
  __syncthreads();
  for (int i = threadIdx.x; i < N_CLS * 128; i += 256) {
    int c = i >> 7, d = i & 127;
    if (d < lim) scores_t[c * N_DET + d0 + d] = tile[d * 81 + c];
  }
}

// ---------------------------------------------------------------------------
// K1: per-class exact top-1000 (score desc, index asc tie-break).
// 2-level radix select (bits[31:21] 2048 bins, then bits[20:13] 256 bins),
// collect candidates >= T (~1010 of them), bitonic sort 2048 packed keys.
// TMODE=1: contiguous reads from scores_t. TMODE=0: strided fallback.
// ---------------------------------------------------------------------------
template <int TMODE>
__global__ __launch_bounds__(256) void k_topk(
    const float* __restrict__ S, const float* __restrict__ boxes,
    float* __restrict__ top_s, float* __restrict__ boxes_s) {
  const int c = blockIdx.x, t = threadIdx.x;
  __shared__ u32 hist[2048];
  __shared__ u32 sfx[256];
  __shared__ u32 sB, sAbove;
  __shared__ u32 scnt;
  __shared__ u64 keys[CAND];

  const float4* S4 = (const float4*)(S + (size_t)c * N_DET);

  // ---- level 0: bits [31:21], 2048 bins
  for (int i = t; i < 2048; i += 256) hist[i] = 0;
  __syncthreads();
  if (TMODE) {
    for (int v = t; v < N_DET / 4; v += 256) {
      float4 f = S4[v];
      atomicAdd(&hist[__float_as_uint(f.x) >> 21], 1u);
      atomicAdd(&hist[__float_as_uint(f.y) >> 21], 1u);
      atomicAdd(&hist[__float_as_uint(f.z) >> 21], 1u);
      atomicAdd(&hist[__float_as_uint(f.w) >> 21], 1u);
    }
  } else {
    for (int i = t; i < N_DET; i += 256)
      atomicAdd(&hist[__float_as_uint(S[(size_t)i * N_CLS + c]) >> 21], 1u);
  }
  __syncthreads();
  u32 target = TOPK;
  u32 loc[8]; u32 gs = 0;
  #pragma unroll
  for (int k = 0; k < 8; ++k) { loc[k] = hist[t * 8 + k]; gs += loc[k]; }
  sfx[t] = gs;
  __syncthreads();
  for (int off = 1; off < 256; off <<= 1) {
    u32 v = (t + off < 256) ? sfx[t + off] : 0u;
    __syncthreads();
    sfx[t] += v;
    __syncthreads();
  }
  {
    u32 above = (t == 255) ? 0u : sfx[t + 1];
    if (above < target && above + gs >= target) {
      u32 run = above;
      #pragma unroll
      for (int k = 7; k >= 0; --k) {
        u32 nr = run + loc[k];
        if (run < target && nr >= target) { sB = (u32)(t * 8 + k); sAbove = run; }
        run = nr;
      }
    }
  }
  __syncthreads();
  const u32 B0 = sB;
  target -= sAbove;
  __syncthreads();

  // ---- level 1: bits [20:13], 256 bins, elements with prefix B0
  hist[t] = 0;
  __syncthreads();
  if (TMODE) {
    for (int v = t; v < N_DET / 4; v += 256) {
      float4 f = S4[v];
      u32 b0 = __float_as_uint(f.x), b1 = __float_as_uint(f.y);
      u32 b2 = __float_as_uint(f.z), b3 = __float_as_uint(f.w);
      if ((b0 >> 21) == B0) atomicAdd(&hist[(b0 >> 13) & 0xFF], 1u);
      if ((b1 >> 21) == B0) atomicAdd(&hist[(b1 >> 13) & 0xFF], 1u);
      if ((b2 >> 21) == B0) atomicAdd(&hist[(b2 >> 13) & 0xFF], 1u);
      if ((b3 >> 21) == B0) atomicAdd(&hist[(b3 >> 13) & 0xFF], 1u);
    }
  } else {
    for (int i = t; i < N_DET; i += 256) {
      u32 b = __float_as_uint(S[(size_t)i * N_CLS + c]);
      if ((b >> 21) == B0) atomicAdd(&hist[(b >> 13) & 0xFF], 1u);
    }
  }
  __syncthreads();
  sfx[t] = hist[t];
  __syncthreads();
  for (int off = 1; off < 256; off <<= 1) {
    u32 v = (t + off < 256) ? sfx[t + off] : 0u;
    __syncthreads();
    sfx[t] += v;
    __syncthreads();
  }
  if (sfx[t] >= target && (t == 255 || sfx[t + 1] < target)) {
    sB = (u32)t;
    sAbove = (t == 255) ? 0u : sfx[t + 1];
  }
  __syncthreads();
  const u32 T = (B0 << 21) | (sB << 13);
  if (t == 0) scnt = 0;
  __syncthreads();

  // ---- collect candidates >= T
  if (TMODE) {
    for (int v = t; v < N_DET / 4; v += 256) {
      float4 f = S4[v];
      u32 bb[4] = {__float_as_uint(f.x), __float_as_uint(f.y),
                   __float_as_uint(f.z), __float_as_uint(f.w)};
      #pragma unroll
      for (int k = 0; k < 4; ++k) {
        if (bb[k] >= T) {
          u32 p = atomicAdd(&scnt, 1u);
          if (p < CAND) keys[p] = ((u64)bb[k] << 32) | (u32)(~(u32)(4 * v + k));
        }
      }
    }
  } else {
    for (int i = t; i < N_DET; i += 256) {
      u32 b = __float_as_uint(S[(size_t)i * N_CLS + c]);
      if (b >= T) {
        u32 p = atomicAdd(&scnt, 1u);
        if (p < CAND) keys[p] = ((u64)b << 32) | (u32)(~(u32)i);
      }
    }
  }
  __syncthreads();
  u32 cnt = scnt < CAND ? scnt : CAND;
  for (int i = t; i < CAND; i += 256)
    if (i >= (int)cnt) keys[i] = 0ull;
  __syncthreads();
  // bitonic sort, descending
  for (int k = 2; k <= CAND; k <<= 1)
    for (int j = k >> 1; j > 0; j >>= 1) {
      for (int p = t; p < CAND / 2; p += 256) {
        int i  = ((p & ~(j - 1)) << 1) | (p & (j - 1));
        int ix = i | j;
        bool up = (i & k) == 0;
        u64 a = keys[i], b = keys[ix];
        if (up ? (a < b) : (a > b)) { keys[i] = b; keys[ix] = a; }
      }
      __syncthreads();
    }
  for (int i = t; i < TOPK; i += 256) {
    u64 kk = keys[i];
    u32 bits = (u32)(kk >> 32);
    u32 idx = ~(u32)kk;
    if (kk == 0ull) idx = 0;  // pad entry (pathological only)
    top_s[c * TOPK + i] = __uint_as_float(bits);
    float4 bx = ((const float4*)boxes)[idx];
    ((float4*)boxes_s)[c * TOPK + i] = bx;
  }
}

// ---------------------------------------------------------------------------
// K2+K3 fused: suppression bitmask in 125 KiB LDS, then serial greedy sweep.
// One block (512 thr, 8 waves) per class. Column boxes cached in registers
// (16 float4 + 16 area per lane, static-indexed via unrolled segment loop).
// ---------------------------------------------------------------------------
__global__ __launch_bounds__(512) void k_nms(
    const float* __restrict__ top_s, const float* __restrict__ boxes_s,
    float* __restrict__ cls_out) {
  const int c = blockIdx.x;
  const int tid = threadIdx.x, wave = tid >> 6, lane = tid & 63;
  __shared__ u64 maskL[TOPK * 16];  // 128000 B

  const float4* B4 = (const float4*)boxes_s + (size_t)c * TOPK;
  float4 cb[16]; float ca[16];
  #pragma unroll
  for (int s = 0; s < 16; ++s) {
    int j = s * 64 + lane;
    float4 b = (j < TOPK) ? B4[j] : make_float4(0.f, 0.f, 0.f, 0.f);
    cb[s] = b;
    ca[s] = (b.z - b.x) * (b.w - b.y);
  }
  // ---- mask phase: rows round-robin across 8 waves
  for (int i = wave; i < TOPK; i += 8) {
    float4 bi = B4[i];
    float ai = (bi.z - bi.x) * (bi.w - bi.y);
    const int s0 = i >> 6;
    u64 w = 0;
    #pragma unroll
    for (int s = 0; s < 16; ++s) {
      if (s >= s0) {
        int j = s * 64 + lane;
        bool sup = false;
        if (j < TOPK && j > i) {
          #pragma clang fp contract(off)
          float iw = fmaxf(fminf(bi.z, cb[s].z) - fmaxf(bi.x, cb[s].x), 0.0f);
          float ih = fmaxf(fminf(bi.w, cb[s].w) - fmaxf(bi.y, cb[s].y), 0.0f);
          float inter = iw * ih;
          float iou = inter / (ai + ca[s] - inter + 1e-9f);
          sup = iou > NMST;
        }
        u64 bal = __ballot(sup);
        if (lane == s) w = bal;
      }
    }
    if (lane < 16) maskL[i * 16 + lane] = w;
  }
  __syncthreads();

  // ---- sweep phase: wave 0 only
  if (wave == 0) {
    u64 keepw = 0;
    for (int s = 0; s < 16; ++s) {
      int j = s * 64 + lane;
      bool valid = (j < TOPK) && (top_s[c * TOPK + j] > CONF);
      u64 bal = __ballot(valid);
      if (lane == s) keepw = bal;
    }
    const bool ld = lane < 16;
    u64 rbuf[8];
    #pragma unroll
    for (int d = 0; d < 8; ++d)
      rbuf[d] = ld ? maskL[d * 16 + lane] : 0ull;
    for (int ib = 0; ib < TOPK; ib += 8) {
      #pragma unroll
      for (int d = 0; d < 8; ++d) {
        const int i = ib + d;
        u64 w = shfl64(keepw, i >> 6);
        if ((w >> (i & 63)) & 1ull) keepw &= ~rbuf[d];
        int nx = ib + 8 + d;
        rbuf[d] = (ld && nx < TOPK) ? maskL[nx * 16 + lane] : 0ull;
      }
    }
    // compact first <=100 kept scores (cls_out pre-zeroed by memset)
    int base = 0;
    for (int s = 0; s < 16; ++s) {
      u64 w = shfl64(keepw, s);
      int pos = base + __popcll(w & ((1ull << lane) - 1ull));
      if (((w >> lane) & 1ull) && pos < 100)
        cls_out[c * 128 + pos] = top_s[c * TOPK + s * 64 + lane];
      base += __popcll(w);
    }
  }
}

// ---------------------------------------------------------------------------
// K4: global top-100 of 80 x (top-100 per class), bitonic sort 8192 in LDS.
// ---------------------------------------------------------------------------
__global__ __launch_bounds__(512) void k_final(
    const float* __restrict__ cls_out, float* __restrict__ out) {
  __shared__ float v[8192];
  const int t = threadIdx.x;
  for (int i = t; i < 8192; i += 512) {
    float x = 0.0f;
    if (i < 8000) x = cls_out[(i / 100) * 128 + (i % 100)];
    v[i] = x;
  }
  __syncthreads();
  for (int k = 2; k <= 8192; k <<= 1)
    for (int j = k >> 1; j > 0; j >>= 1) {
      for (int p = t; p < 4096; p += 512) {
        int i  = ((p & ~(j - 1)) << 1) | (p & (j - 1));
        int ix = i | j;
        bool up = (i & k) == 0;
        float a = v[i], b = v[ix];
        if (up ? (a < b) : (a > b)) { v[i] = b; v[ix] = a; }
      }
      __syncthreads();
    }
  if (t < 100) out[t] = v[t];
}

// ---------------------------------------------------------------------------
// Fast path (ws >= 8.05 MB):
//   scores_t : 80*20000 f32   @ 0         (6400000 B)
//   top_s    : 80*1000 f32    @ 6400000   (320000 B)
//   boxes_s  : 80*1000 float4 @ 6720000   (1280000 B)
//   cls_out  : 80*128 f32     @ 8000000   (40960 B)   -> end 8040960
// Fallback (ws >= 1.65 MB): top_s @0, boxes_s @320000, cls_out @1600000
// ---------------------------------------------------------------------------
extern "C" void kernel_launch(void* const* d_in, const int* in_sizes, int n_in,
                              void* d_out, int out_size, void* d_ws, size_t ws_size,
                              hipStream_t stream) {
  const float* scores = (const float*)d_in[0];
  const float* boxes  = (const float*)d_in[1];
  float* out = (float*)d_out;
  char* ws = (char*)d_ws;

  const bool fast = (ws_size >= 8040960u);
  float* scores_t = (float*)ws;
  float* top_s    = (float*)(ws + (fast ? 6400000 : 0));
  float* boxes_s  = (float*)(ws + (fast ? 6720000 : 320000));
  float* cls_out  = (float*)(ws + (fast ? 8000000 : 1600000));

  hipMemsetAsync(cls_out, 0, N_CLS * 128 * sizeof(float), stream);
  if (fast) {
    k_transpose<<<(N_DET + 127) / 128, 256, 0, stream>>>(scores, scores_t);
    k_topk<1><<<N_CLS, 256, 0, stream>>>(scores_t, boxes, top_s, boxes_s);
  } else {
    k_topk<0><<<N_CLS, 256, 0, stream>>>(scores, boxes, top_s, boxes_s);
  }
  k_nms<<<N_CLS, 512, 0, stream>>>(top_s, boxes_s, cls_out);
  k_final<<<1, 512, 0, stream>>>(cls_out, out);
}